// Round 4
// baseline (2265.315 us; speedup 1.0000x reference)
//
#include <hip/hip_runtime.h>
#include <hip/hip_cooperative_groups.h>
#include <math.h>

namespace cg = cooperative_groups;

#define V 30000
#define H 512
#define NB 16
#define NS 256
#define NJ 10
#define NT 8
#define NOPS 4
#define NR 160          // NJ*NB rows
#define EV 30720        // padded E row stride
#define NEGV -1e9f

typedef __attribute__((ext_vector_type(8))) short short8;
typedef __attribute__((ext_vector_type(4))) short short4v;
typedef __attribute__((ext_vector_type(4))) float f32x4;

__device__ inline float bf2f(unsigned short s) {
    union { unsigned int u; float f; } c; c.u = ((unsigned int)s) << 16;
    return c.f;
}
__device__ inline unsigned short f2bf(float f) {
    union { float f; unsigned int u; } c; c.f = f;
    unsigned int u = c.u;
    u += 0x7fffu + ((u >> 16) & 1u);   // RNE
    return (unsigned short)(u >> 16);
}
__device__ inline unsigned long long packkey(float f, int v) {
    union { float f; unsigned int u; } c; c.f = f;
    return ((unsigned long long)c.u << 32) | (unsigned int)(0x7FFFFFFF - v);
}

// ---------------- setup: convert emb_W to bf16 ----------------
__global__ void k_setup_emb(const float* __restrict__ emb, unsigned short* __restrict__ emb_bf, int n8) {
    int gid = blockIdx.x * 256 + threadIdx.x;
    if (gid >= n8) return;
    const float4* src = (const float4*)emb + (size_t)gid * 2;
    float4 a = src[0], b = src[1];
    short8 o;
    o[0] = (short)f2bf(a.x); o[1] = (short)f2bf(a.y); o[2] = (short)f2bf(a.z); o[3] = (short)f2bf(a.w);
    o[4] = (short)f2bf(b.x); o[5] = (short)f2bf(b.y); o[6] = (short)f2bf(b.z); o[7] = (short)f2bf(b.w);
    *(short8*)(emb_bf + (size_t)gid * 8) = o;
}

// ---------------- setup: W splits + initial w/h state ----------------
__global__ void k_setup_small(const float* __restrict__ Wih, const float* __restrict__ Whh,
    unsigned short* wih_hi, unsigned short* wih_lo, unsigned short* whh_hi, unsigned short* whh_lo,
    const float* __restrict__ slot, const float* __restrict__ ench,
    float* w_g, unsigned short* w_hi, unsigned short* w_lo,
    float* h_g, unsigned short* h_hi, unsigned short* h_lo)
{
    int gid = blockIdx.x * 256 + threadIdx.x;
    if (gid < 786432) {
        float v1 = Wih[gid];
        unsigned short hi = f2bf(v1);
        wih_hi[gid] = hi; wih_lo[gid] = f2bf(v1 - bf2f(hi));
        float v2 = Whh[gid];
        hi = f2bf(v2);
        whh_hi[gid] = hi; whh_lo[gid] = f2bf(v2 - bf2f(hi));
    } else {
        int i = gid - 786432;
        if (i < NR * H) {
            int jb = i >> 9, d = i & 511;
            int j = jb >> 4, b = jb & 15;
            float wv = slot[j * H + d];
            w_g[i] = wv;
            unsigned short hi = f2bf(wv);
            w_hi[i] = hi; w_lo[i] = f2bf(wv - bf2f(hi));
            float hv = ench[b * H + d];
            h_g[i] = hv;
            hi = f2bf(hv);
            h_hi[i] = hi; h_lo[i] = f2bf(hv - bf2f(hi));
        }
    }
}

struct DecArgs {
    const int* x;
    const float* enc;
    const float* embW;
    const float* bih; const float* bhh;
    const float* wgenW; const float* wgenb;
    const float* aW; const float* ab;
    const unsigned short* emb_bf;
    const unsigned short* wih_hi; const unsigned short* wih_lo;
    const unsigned short* whh_hi; const unsigned short* whh_lo;
    float* w_g; float* h_g; float* ctx0;
    unsigned short* w_hi; unsigned short* w_lo;
    unsigned short* h_hi; unsigned short* h_lo;
    float* gi; float* gh;
    float* attn; float* pgen;
    float* rowsum; unsigned long long* argpk;
    unsigned short* E;
    float* out;
};

// ---------------- phase: GRU GEMMs (tasks 0..239) ----------------
#define GRU_APAD 520
__device__ void phase_gru(int task, const DecArgs& P, unsigned char* smem) {
    unsigned short* Ah = (unsigned short*)smem;              // 16*520*2 = 16640 B
    unsigned short* Al = (unsigned short*)(smem + 16640);
    int nch = task % 12, mt = (task / 12) % 10, z = task / 120;
    const unsigned short* Asrc_hi = z ? P.h_hi : P.w_hi;
    const unsigned short* Asrc_lo = z ? P.h_lo : P.w_lo;
    const unsigned short* Bhi = z ? P.whh_hi : P.wih_hi;
    const unsigned short* Blo = z ? P.whh_lo : P.wih_lo;
    float* outp = z ? P.gh : P.gi;
    int t = threadIdx.x;
    for (int i = t; i < 2048; i += 256) {
        int matl = i >> 10;
        int row = (i >> 6) & 15;
        int seg = i & 63;
        const unsigned short* src = (matl ? Asrc_lo : Asrc_hi) + (mt * 16 + row) * 512 + seg * 8;
        unsigned short* dst = (matl ? Al : Ah) + row * GRU_APAD + seg * 8;
        *(short8*)dst = *(const short8*)src;
    }
    __syncthreads();
    int wv = t >> 6, lane = t & 63;
    int col15 = lane & 15, quad = lane >> 4;
    f32x4 acc0 = {0.f, 0.f, 0.f, 0.f}, acc1 = {0.f, 0.f, 0.f, 0.f};
    int c0 = nch * 128 + wv * 32 + col15;
    int c1 = c0 + 16;
    const unsigned short* bhp0 = Bhi + c0 * 512 + quad * 8;
    const unsigned short* bhp1 = Bhi + c1 * 512 + quad * 8;
    const unsigned short* blp0 = Blo + c0 * 512 + quad * 8;
    const unsigned short* blp1 = Blo + c1 * 512 + quad * 8;
    const unsigned short* ahp = Ah + col15 * GRU_APAD + quad * 8;
    const unsigned short* alp = Al + col15 * GRU_APAD + quad * 8;
#pragma unroll
    for (int ks = 0; ks < 16; ks++) {
        int ko = ks * 32;
        short8 bh0 = *(const short8*)(bhp0 + ko);
        short8 bh1 = *(const short8*)(bhp1 + ko);
        short8 bl0 = *(const short8*)(blp0 + ko);
        short8 bl1 = *(const short8*)(blp1 + ko);
        short8 ah = *(const short8*)(ahp + ko);
        short8 al = *(const short8*)(alp + ko);
        acc0 = __builtin_amdgcn_mfma_f32_16x16x32_bf16(ah, bh0, acc0, 0, 0, 0);
        acc1 = __builtin_amdgcn_mfma_f32_16x16x32_bf16(ah, bh1, acc1, 0, 0, 0);
        acc0 = __builtin_amdgcn_mfma_f32_16x16x32_bf16(ah, bl0, acc0, 0, 0, 0);
        acc1 = __builtin_amdgcn_mfma_f32_16x16x32_bf16(ah, bl1, acc1, 0, 0, 0);
        acc0 = __builtin_amdgcn_mfma_f32_16x16x32_bf16(al, bh0, acc0, 0, 0, 0);
        acc1 = __builtin_amdgcn_mfma_f32_16x16x32_bf16(al, bh1, acc1, 0, 0, 0);
    }
#pragma unroll
    for (int r = 0; r < 4; r++) {
        int row = mt * 16 + quad * 4 + r;
        outp[row * 1536 + c0] = acc0[r];
        outp[row * 1536 + c1] = acc1[r];
    }
}

// ---------------- phase: GRU pointwise + attention + softmax + context + p_gen ----------------
__device__ void phase_attention(int jb, const DecArgs& P, unsigned char* smem, int store_ctx) {
    float* h_lds = (float*)smem;                 // 512 f
    float* sc    = (float*)(smem + 2048);        // 256 f
    float* red   = (float*)(smem + 3072);        // 256 f
    float* ctxp  = (float*)(smem + 4096);        // 2048 f
    int b = jb & 15;
    int t = threadIdx.x;
    if (t == 0) { P.rowsum[jb] = 0.f; P.argpk[jb] = 0ull; }   // zero for this step's vgemm
    for (int d = t; d < 512; d += 256) {
        int base = jb * 1536;
        float ir = P.gi[base + d]        + P.bih[d];
        float iz = P.gi[base + 512 + d]  + P.bih[512 + d];
        float in = P.gi[base + 1024 + d] + P.bih[1024 + d];
        float hr = P.gh[base + d]        + P.bhh[d];
        float hz = P.gh[base + 512 + d]  + P.bhh[512 + d];
        float hn = P.gh[base + 1024 + d] + P.bhh[1024 + d];
        float hold = P.h_g[jb * 512 + d];
        float r = 1.f / (1.f + expf(-(ir + hr)));
        float z = 1.f / (1.f + expf(-(iz + hz)));
        float n = tanhf(in + r * hn);
        float hnew = (1.f - z) * n + z * hold;
        h_lds[d] = hnew;
        P.h_g[jb * 512 + d] = hnew;
        unsigned short hi = f2bf(hnew);
        P.h_hi[jb * 512 + d] = hi;
        P.h_lo[jb * 512 + d] = f2bf(hnew - bf2f(hi));
    }
    __syncthreads();
    int wid = t >> 6, lane = t & 63;
    float hreg[8];
#pragma unroll
    for (int i = 0; i < 8; i++) hreg[i] = h_lds[lane * 8 + i];
    const float* encb = P.enc + (size_t)b * NS * H;
    for (int s = wid; s < NS; s += 4) {
        const float4* er = (const float4*)(encb + s * 512 + lane * 8);
        float4 e0 = er[0], e1 = er[1];
        float p = e0.x * hreg[0] + e0.y * hreg[1] + e0.z * hreg[2] + e0.w * hreg[3]
                + e1.x * hreg[4] + e1.y * hreg[5] + e1.z * hreg[6] + e1.w * hreg[7];
#pragma unroll
        for (int off = 32; off > 0; off >>= 1) p += __shfl_down(p, off);
        if (lane == 0) sc[s] = (P.x[b * NS + s] == 0) ? NEGV : p;
    }
    __syncthreads();
    red[t] = sc[t];
    __syncthreads();
    for (int sft = 128; sft > 0; sft >>= 1) { if (t < sft) red[t] = fmaxf(red[t], red[t + sft]); __syncthreads(); }
    float m = red[0];
    __syncthreads();
    float e = expf(sc[t] - m);
    red[t] = e;
    __syncthreads();
    for (int sft = 128; sft > 0; sft >>= 1) { if (t < sft) red[t] += red[t + sft]; __syncthreads(); }
    float inv = 1.f / red[0];
    float p_s = e * inv;
    sc[t] = p_s;
    P.attn[jb * NS + t] = p_s;
    __syncthreads();
    {
        float cp[8] = {0.f,0.f,0.f,0.f,0.f,0.f,0.f,0.f};
        const float* encw = encb + lane * 8;
        for (int s = wid * 64; s < wid * 64 + 64; s++) {
            float ps = sc[s];
            const float4* er = (const float4*)(encw + s * 512);
            float4 e0 = er[0], e1 = er[1];
            cp[0] += ps * e0.x; cp[1] += ps * e0.y; cp[2] += ps * e0.z; cp[3] += ps * e0.w;
            cp[4] += ps * e1.x; cp[5] += ps * e1.y; cp[6] += ps * e1.z; cp[7] += ps * e1.w;
        }
        float* cw = ctxp + wid * 512 + lane * 8;
#pragma unroll
        for (int i = 0; i < 8; i++) cw[i] = cp[i];
    }
    __syncthreads();
    int d0 = 2 * t, d1 = 2 * t + 1;
    float c0 = ctxp[d0] + ctxp[512 + d0] + ctxp[1024 + d0] + ctxp[1536 + d0];
    float c1 = ctxp[d1] + ctxp[512 + d1] + ctxp[1024 + d1] + ctxp[1536 + d1];
    if (store_ctx) ((float2*)P.ctx0)[jb * 256 + t] = make_float2(c0, c1);
    float pg = P.wgenW[d0] * P.w_g[jb * 512 + d0] + P.wgenW[d1] * P.w_g[jb * 512 + d1]
             + P.wgenW[512 + d0] * h_lds[d0] + P.wgenW[512 + d1] * h_lds[d1]
             + P.wgenW[1024 + d0] * c0 + P.wgenW[1024 + d1] * c1;
    __syncthreads();
    red[t] = pg;
    __syncthreads();
    for (int sft = 128; sft > 0; sft >>= 1) { if (t < sft) red[t] += red[t + sft]; __syncthreads(); }
    if (t == 0) P.pgen[jb] = 1.f / (1.f + expf(-(red[0] + P.wgenb[0])));
}

// ---------------- phase: vocab GEMM + exp + rowsum + dense argmax (tasks 0..239) ----------------
#define VPAD 136
__device__ void phase_vgemm(int blk, const DecArgs& P, unsigned char* smem) {
    unsigned short* A = (unsigned short*)smem;   // 160*136*2 = 43520 B
    int t = threadIdx.x;
    int wv = t >> 6, lane = t & 63, col15 = lane & 15, quad = lane >> 4;
    int v = blk * 128 + wv * 32 + col15;
    f32x4 acc[10][2];
#pragma unroll
    for (int m = 0; m < 10; m++) {
        acc[m][0] = (f32x4){0.f, 0.f, 0.f, 0.f};
        acc[m][1] = (f32x4){0.f, 0.f, 0.f, 0.f};
    }
    int v0c = min(v, V - 1);
    int v1c = min(v + 16, V - 1);
    for (int kc = 0; kc < 4; kc++) {
        __syncthreads();
        for (int i = t; i < 2560; i += 256) {
            int row = i >> 4, seg = i & 15;
            *(short8*)(A + row * VPAD + seg * 8) = *(const short8*)(P.h_hi + row * 512 + kc * 128 + seg * 8);
        }
        __syncthreads();
#pragma unroll
        for (int ks = 0; ks < 4; ks++) {
            int kl = ks * 32 + quad * 8;
            int kg = kc * 128 + kl;
            short8 b0 = *(const short8*)(P.emb_bf + (size_t)v0c * 512 + kg);
            short8 b1 = *(const short8*)(P.emb_bf + (size_t)v1c * 512 + kg);
#pragma unroll
            for (int m = 0; m < 10; m++) {
                short8 a = *(const short8*)(A + (m * 16 + col15) * VPAD + kl);
                acc[m][0] = __builtin_amdgcn_mfma_f32_16x16x32_bf16(a, b0, acc[m][0], 0, 0, 0);
                acc[m][1] = __builtin_amdgcn_mfma_f32_16x16x32_bf16(a, b1, acc[m][1], 0, 0, 0);
            }
        }
    }
    __syncthreads();
    // exp + transpose into LDS
#pragma unroll
    for (int m = 0; m < 10; m++) {
#pragma unroll
        for (int tile = 0; tile < 2; tile++) {
            int vv = v + tile * 16;
            int cl = wv * 32 + tile * 16 + col15;
#pragma unroll
            for (int r = 0; r < 4; r++) {
                int row = m * 16 + quad * 4 + r;
                float ev = (vv < V) ? expf(acc[m][tile][r]) : 0.f;
                A[row * VPAD + cl] = f2bf(ev);
            }
        }
    }
    __syncthreads();
    if (t < 160) {
        float s = 0.f;
        unsigned long long key = 0ull;
#pragma unroll
        for (int seg = 0; seg < 16; seg++) {
            short8 ev = *(const short8*)(A + t * VPAD + seg * 8);
#pragma unroll
            for (int k = 0; k < 8; k++) {
                float f = bf2f((unsigned short)ev[k]);
                s += f;
                unsigned long long kk = packkey(f, blk * 128 + seg * 8 + k);
                key = (kk > key) ? kk : key;
            }
        }
        atomicAdd(P.rowsum + t, s);
        atomicMax(P.argpk + t, key);
    }
    {
        int rsub = t >> 4, seg = t & 15;
        for (int it = 0; it < 10; it++) {
            int row = it * 16 + rsub;
            short8 ev = *(const short8*)(A + row * VPAD + seg * 8);
            *(short8*)(P.E + (size_t)row * EV + blk * 128 + seg * 8) = ev;
        }
    }
}

// ---------------- phase: finalize (tasks 0..159) ----------------
__device__ void phase_finalize(int jb, const DecArgs& P, unsigned char* smem, int tstep) {
    float* bvs = (float*)smem;
    int* bis   = (int*)(smem + 1024);
    float* red = (float*)(smem + 2048);
    int t = threadIdx.x;
    int j = jb >> 4, b = jb & 15;
    float inv = 1.f / P.rowsum[jb];
    float pgen = P.pgen[jb];
    float scale = pgen * inv;
    const unsigned short* Er = P.E + (size_t)jb * EV;
    size_t outbase = (size_t)640 + ((size_t)(b * NJ + j) * NT + tstep) * V;
    float* op = P.out + outbase;
    for (int c = 0; c < 29; c++) {
        int vv = c * 1024 + t * 4;
        short4v e = *(const short4v*)(Er + vv);
        float4 p = make_float4(bf2f((unsigned short)e[0]) * scale, bf2f((unsigned short)e[1]) * scale,
                               bf2f((unsigned short)e[2]) * scale, bf2f((unsigned short)e[3]) * scale);
        *(float4*)(op + vv) = p;
    }
    if (t < 76) {
        int vv = 29696 + t * 4;
        short4v e = *(const short4v*)(Er + vv);
        float4 p = make_float4(bf2f((unsigned short)e[0]) * scale, bf2f((unsigned short)e[1]) * scale,
                               bf2f((unsigned short)e[2]) * scale, bf2f((unsigned short)e[3]) * scale);
        *(float4*)(op + vv) = p;
    }
    __syncthreads();   // dense stores drained before scatter atomics
    float best; int besti;
    {
        int vv = P.x[b * NS + t];
        float a = (1.f - pgen) * P.attn[jb * NS + t];
        float old = atomicAdd(&op[vv], a);
        best = old + a;
        besti = vv;
    }
    bvs[t] = best; bis[t] = besti;
    __syncthreads();
    for (int sft = 128; sft > 0; sft >>= 1) {
        if (t < sft) {
            if (bvs[t + sft] > bvs[t] || (bvs[t + sft] == bvs[t] && bis[t + sft] < bis[t])) {
                bvs[t] = bvs[t + sft]; bis[t] = bis[t + sft];
            }
        }
        __syncthreads();
    }
    int widx;
    {
        unsigned long long key = P.argpk[jb];
        union { unsigned int u; float f; } c; c.u = (unsigned int)(key >> 32);
        float db = c.f * scale;
        int di = 0x7FFFFFFF - (int)(key & 0xFFFFFFFFu);
        float sb = bvs[0]; int si = bis[0];
        widx = (sb > db || (sb == db && si < di)) ? si : di;
    }
    for (int d = t; d < 512; d += 256) {
        float val = P.embW[(size_t)widx * 512 + d];
        P.w_g[jb * 512 + d] = val;
        unsigned short hi = f2bf(val);
        P.w_hi[jb * 512 + d] = hi;
        P.w_lo[jb * 512 + d] = f2bf(val - bf2f(hi));
    }
    if (tstep == 0) {
        float part[4] = {0.f, 0.f, 0.f, 0.f};
        for (int d = t; d < 512; d += 256) {
            float c = P.ctx0[jb * 512 + d];
#pragma unroll
            for (int o = 0; o < 4; o++) part[o] += c * P.aW[o * 512 + d];
        }
        for (int o = 0; o < 4; o++) {
            __syncthreads();
            red[t] = part[o];
            __syncthreads();
            for (int sft = 128; sft > 0; sft >>= 1) { if (t < sft) red[t] += red[t + sft]; __syncthreads(); }
            if (t == 0) P.out[(b * NJ + j) * NOPS + o] = red[0] + P.ab[o];
        }
    }
}

// ---------------- persistent cooperative decode kernel ----------------
__global__ __launch_bounds__(256, 2) void k_decode(DecArgs P) {
    cg::grid_group grid = cg::this_grid();
    __shared__ __align__(16) unsigned char smem[43520];
    int blk = blockIdx.x;
    for (int t = 0; t < NT; t++) {
        if (blk < 240) phase_gru(blk, P, smem);
        grid.sync();
        if (blk < 160) phase_attention(blk, P, smem, t == 0 ? 1 : 0);
        grid.sync();
        if (blk < 240) phase_vgemm(blk, P, smem);
        grid.sync();
        if (blk < 160) phase_finalize(blk, P, smem, t);
        grid.sync();
    }
}

extern "C" void kernel_launch(void* const* d_in, const int* in_sizes, int n_in,
                              void* d_out, int out_size, void* d_ws, size_t ws_size,
                              hipStream_t stream) {
    const int*   x     = (const int*)d_in[0];
    const float* enc   = (const float*)d_in[1];
    const float* ench  = (const float*)d_in[2];
    const float* embW  = (const float*)d_in[4];
    const float* slot  = (const float*)d_in[5];
    const float* Wih   = (const float*)d_in[6];
    const float* Whh   = (const float*)d_in[7];
    const float* bih   = (const float*)d_in[8];
    const float* bhh   = (const float*)d_in[9];
    const float* wgenW = (const float*)d_in[10];
    const float* wgenb = (const float*)d_in[11];
    const float* aW    = (const float*)d_in[12];
    const float* ab    = (const float*)d_in[13];
    float* out = (float*)d_out;

    char* ws = (char*)d_ws;
    size_t off = 0;
    auto carve = [&](size_t bytes) { char* p = ws + off; off += (bytes + 255) & ~(size_t)255; return p; };
    unsigned short* emb_bf = (unsigned short*)carve((size_t)V * H * 2);
    unsigned short* wih_hi = (unsigned short*)carve(786432 * 2);
    unsigned short* wih_lo = (unsigned short*)carve(786432 * 2);
    unsigned short* whh_hi = (unsigned short*)carve(786432 * 2);
    unsigned short* whh_lo = (unsigned short*)carve(786432 * 2);
    float* w_f32 = (float*)carve(NR * H * 4);
    float* h_f32 = (float*)carve(NR * H * 4);
    float* ctx0  = (float*)carve(NR * H * 4);
    unsigned short* w_hi = (unsigned short*)carve(NR * H * 2);
    unsigned short* w_lo = (unsigned short*)carve(NR * H * 2);
    unsigned short* h_hi = (unsigned short*)carve(NR * H * 2);
    unsigned short* h_lo = (unsigned short*)carve(NR * H * 2);
    float* gi   = (float*)carve(NR * 1536 * 4);
    float* gh   = (float*)carve(NR * 1536 * 4);
    float* attn = (float*)carve(NR * NS * 4);
    float* pgen = (float*)carve(NR * 4);
    float* rowsum = (float*)carve(NR * 4);
    unsigned long long* argpk = (unsigned long long*)carve(NR * 8);
    unsigned short* E = (unsigned short*)carve((size_t)NR * EV * 2);

    k_setup_emb<<<7500, 256, 0, stream>>>(embW, emb_bf, (V * H) / 8);
    k_setup_small<<<3392, 256, 0, stream>>>(Wih, Whh, wih_hi, wih_lo, whh_hi, whh_lo,
                                            slot, ench, w_f32, w_hi, w_lo, h_f32, h_hi, h_lo);

    DecArgs P;
    P.x = x; P.enc = enc; P.embW = embW;
    P.bih = bih; P.bhh = bhh; P.wgenW = wgenW; P.wgenb = wgenb;
    P.aW = aW; P.ab = ab;
    P.emb_bf = emb_bf;
    P.wih_hi = wih_hi; P.wih_lo = wih_lo; P.whh_hi = whh_hi; P.whh_lo = whh_lo;
    P.w_g = w_f32; P.h_g = h_f32; P.ctx0 = ctx0;
    P.w_hi = w_hi; P.w_lo = w_lo; P.h_hi = h_hi; P.h_lo = h_lo;
    P.gi = gi; P.gh = gh; P.attn = attn; P.pgen = pgen;
    P.rowsum = rowsum; P.argpk = argpk; P.E = E; P.out = out;

    void* kargs[] = { (void*)&P };
    (void)hipLaunchCooperativeKernel((const void*)k_decode, dim3(240), dim3(256), kargs, 0, stream);
}

// Round 5
// 2212.370 us; speedup vs baseline: 1.0239x; 1.0239x over previous
//
#include <hip/hip_runtime.h>
#include <math.h>

#define V 30000
#define H 512
#define NB 16
#define NS 256
#define NJ 10
#define NT 8
#define NOPS 4
#define NR 160          // NJ*NB rows
#define NBLK 240
#define NEGV -1e9f

typedef __attribute__((ext_vector_type(8))) short short8;
typedef __attribute__((ext_vector_type(4))) float f32x4;

__device__ inline float bf2f(unsigned short s) {
    union { unsigned int u; float f; } c; c.u = ((unsigned int)s) << 16;
    return c.f;
}
__device__ inline unsigned short f2bf(float f) {
    union { float f; unsigned int u; } c; c.f = f;
    unsigned int u = c.u;
    u += 0x7fffu + ((u >> 16) & 1u);   // RNE
    return (unsigned short)(u >> 16);
}
__device__ inline unsigned long long packkey(float f, int v) {
    union { float f; unsigned int u; } c; c.f = f;
    return ((unsigned long long)c.u << 32) | (unsigned int)(0x7FFFFFFF - v);
}

// ---------------- setup: convert emb_W to bf16 ----------------
__global__ void k_setup_emb(const float* __restrict__ emb, unsigned short* __restrict__ emb_bf, int n8) {
    int gid = blockIdx.x * 256 + threadIdx.x;
    if (gid >= n8) return;
    const float4* src = (const float4*)emb + (size_t)gid * 2;
    float4 a = src[0], b = src[1];
    short8 o;
    o[0] = (short)f2bf(a.x); o[1] = (short)f2bf(a.y); o[2] = (short)f2bf(a.z); o[3] = (short)f2bf(a.w);
    o[4] = (short)f2bf(b.x); o[5] = (short)f2bf(b.y); o[6] = (short)f2bf(b.z); o[7] = (short)f2bf(b.w);
    *(short8*)(emb_bf + (size_t)gid * 8) = o;
}

// ---------------- setup: W splits + initial w/h state + zero barriers/sums ----------------
__global__ void k_setup_small(const float* __restrict__ Wih, const float* __restrict__ Whh,
    unsigned short* wih_hi, unsigned short* wih_lo, unsigned short* whh_hi, unsigned short* whh_lo,
    const float* __restrict__ slot, const float* __restrict__ ench,
    float* w_g, unsigned short* w_hi, unsigned short* w_lo,
    float* h_g, unsigned short* h_hi, unsigned short* h_lo,
    unsigned int* bars, float* rowsum8, unsigned long long* argpk8)
{
    int gid = blockIdx.x * 256 + threadIdx.x;
    if (gid < 786432) {
        float v1 = Wih[gid];
        unsigned short hi = f2bf(v1);
        wih_hi[gid] = hi; wih_lo[gid] = f2bf(v1 - bf2f(hi));
        float v2 = Whh[gid];
        hi = f2bf(v2);
        whh_hi[gid] = hi; whh_lo[gid] = f2bf(v2 - bf2f(hi));
    } else if (gid < 786432 + NR * H) {
        int i = gid - 786432;
        int jb = i >> 9, d = i & 511;
        int j = jb >> 4, b = jb & 15;
        float wv = slot[j * H + d];
        w_g[i] = wv;
        unsigned short hi = f2bf(wv);
        w_hi[i] = hi; w_lo[i] = f2bf(wv - bf2f(hi));
        float hv = ench[b * H + d];
        h_g[i] = hv;
        hi = f2bf(hv);
        h_hi[i] = hi; h_lo[i] = f2bf(hv - bf2f(hi));
    } else {
        int i2 = gid - (786432 + NR * H);
        if (i2 < 64) bars[i2] = 0u;
        else if (i2 < 64 + NT * NR) rowsum8[i2 - 64] = 0.f;
        else if (i2 < 64 + 2 * NT * NR) argpk8[i2 - 64 - NT * NR] = 0ull;
    }
}

struct DecArgs {
    const int* x;
    const float* enc;
    const float* embW;
    const float* bih; const float* bhh;
    const float* wgenW; const float* wgenb;
    const float* aW; const float* ab;
    const unsigned short* emb_bf;
    const unsigned short* wih_hi; const unsigned short* wih_lo;
    const unsigned short* whh_hi; const unsigned short* whh_lo;
    float* w_g; float* h_g; float* ctx0;
    unsigned short* w_hi; unsigned short* w_lo;
    unsigned short* h_hi; unsigned short* h_lo;
    float* gi; float* gh;
    float* attn8; float* pgen8;
    float* rowsum8; unsigned long long* argpk8;
    unsigned int* bars;
    float* out;
};

// ---------------- lightweight grid barrier (agent-scope) ----------------
__device__ inline void gbar(unsigned int* ctr) {
    __syncthreads();   // emits vmcnt(0): every wave's stores/atomics are in L2 before tid0 fences
    if (threadIdx.x == 0) {
        __builtin_amdgcn_fence(__ATOMIC_RELEASE, "agent");          // L2 writeback -> device-visible
        __hip_atomic_fetch_add(ctr, 1u, __ATOMIC_RELAXED, __HIP_MEMORY_SCOPE_AGENT);
        while (__hip_atomic_load(ctr, __ATOMIC_RELAXED, __HIP_MEMORY_SCOPE_AGENT) < (unsigned)NBLK)
            __builtin_amdgcn_s_sleep(16);
        __builtin_amdgcn_fence(__ATOMIC_ACQUIRE, "agent");          // invalidate L1/L2 tags
    }
    __syncthreads();
}

// ---------------- phase: GRU GEMMs (tasks 0..239) ----------------
#define GRU_APAD 520
__device__ void phase_gru(int task, const DecArgs& P, unsigned char* smem) {
    unsigned short* Ah = (unsigned short*)smem;              // 16*520*2 = 16640 B
    unsigned short* Al = (unsigned short*)(smem + 16640);
    int nch = task % 12, mt = (task / 12) % 10, z = task / 120;
    const unsigned short* Asrc_hi = z ? P.h_hi : P.w_hi;
    const unsigned short* Asrc_lo = z ? P.h_lo : P.w_lo;
    const unsigned short* Bhi = z ? P.whh_hi : P.wih_hi;
    const unsigned short* Blo = z ? P.whh_lo : P.wih_lo;
    float* outp = z ? P.gh : P.gi;
    int t = threadIdx.x;
    for (int i = t; i < 2048; i += 256) {
        int matl = i >> 10;
        int row = (i >> 6) & 15;
        int seg = i & 63;
        const unsigned short* src = (matl ? Asrc_lo : Asrc_hi) + (mt * 16 + row) * 512 + seg * 8;
        unsigned short* dst = (matl ? Al : Ah) + row * GRU_APAD + seg * 8;
        *(short8*)dst = *(const short8*)src;
    }
    __syncthreads();
    int wv = t >> 6, lane = t & 63;
    int col15 = lane & 15, quad = lane >> 4;
    f32x4 acc0 = {0.f, 0.f, 0.f, 0.f}, acc1 = {0.f, 0.f, 0.f, 0.f};
    int c0 = nch * 128 + wv * 32 + col15;
    int c1 = c0 + 16;
    const unsigned short* bhp0 = Bhi + c0 * 512 + quad * 8;
    const unsigned short* bhp1 = Bhi + c1 * 512 + quad * 8;
    const unsigned short* blp0 = Blo + c0 * 512 + quad * 8;
    const unsigned short* blp1 = Blo + c1 * 512 + quad * 8;
    const unsigned short* ahp = Ah + col15 * GRU_APAD + quad * 8;
    const unsigned short* alp = Al + col15 * GRU_APAD + quad * 8;
#pragma unroll
    for (int ks = 0; ks < 16; ks++) {
        int ko = ks * 32;
        short8 bh0 = *(const short8*)(bhp0 + ko);
        short8 bh1 = *(const short8*)(bhp1 + ko);
        short8 bl0 = *(const short8*)(blp0 + ko);
        short8 bl1 = *(const short8*)(blp1 + ko);
        short8 ah = *(const short8*)(ahp + ko);
        short8 al = *(const short8*)(alp + ko);
        acc0 = __builtin_amdgcn_mfma_f32_16x16x32_bf16(ah, bh0, acc0, 0, 0, 0);
        acc1 = __builtin_amdgcn_mfma_f32_16x16x32_bf16(ah, bh1, acc1, 0, 0, 0);
        acc0 = __builtin_amdgcn_mfma_f32_16x16x32_bf16(ah, bl0, acc0, 0, 0, 0);
        acc1 = __builtin_amdgcn_mfma_f32_16x16x32_bf16(ah, bl1, acc1, 0, 0, 0);
        acc0 = __builtin_amdgcn_mfma_f32_16x16x32_bf16(al, bh0, acc0, 0, 0, 0);
        acc1 = __builtin_amdgcn_mfma_f32_16x16x32_bf16(al, bh1, acc1, 0, 0, 0);
    }
#pragma unroll
    for (int r = 0; r < 4; r++) {
        int row = mt * 16 + quad * 4 + r;
        outp[row * 1536 + c0] = acc0[r];
        outp[row * 1536 + c1] = acc1[r];
    }
}

// ---------------- phase: GRU pointwise + attention + softmax + context + p_gen ----------------
__device__ void phase_attention(int jb, const DecArgs& P, unsigned char* smem, int tstep) {
    float* h_lds = (float*)smem;                 // 512 f
    float* sc    = (float*)(smem + 2048);        // 256 f
    float* red   = (float*)(smem + 3072);        // 256 f
    float* ctxp  = (float*)(smem + 4096);        // 2048 f
    int b = jb & 15;
    int t = threadIdx.x;
    for (int d = t; d < 512; d += 256) {
        int base = jb * 1536;
        float ir = P.gi[base + d]        + P.bih[d];
        float iz = P.gi[base + 512 + d]  + P.bih[512 + d];
        float in = P.gi[base + 1024 + d] + P.bih[1024 + d];
        float hr = P.gh[base + d]        + P.bhh[d];
        float hz = P.gh[base + 512 + d]  + P.bhh[512 + d];
        float hn = P.gh[base + 1024 + d] + P.bhh[1024 + d];
        float hold = P.h_g[jb * 512 + d];
        float r = 1.f / (1.f + expf(-(ir + hr)));
        float z = 1.f / (1.f + expf(-(iz + hz)));
        float n = tanhf(in + r * hn);
        float hnew = (1.f - z) * n + z * hold;
        h_lds[d] = hnew;
        P.h_g[jb * 512 + d] = hnew;
        unsigned short hi = f2bf(hnew);
        P.h_hi[jb * 512 + d] = hi;
        P.h_lo[jb * 512 + d] = f2bf(hnew - bf2f(hi));
    }
    __syncthreads();
    int wid = t >> 6, lane = t & 63;
    float hreg[8];
#pragma unroll
    for (int i = 0; i < 8; i++) hreg[i] = h_lds[lane * 8 + i];
    const float* encb = P.enc + (size_t)b * NS * H;
    for (int s = wid; s < NS; s += 4) {
        const float4* er = (const float4*)(encb + s * 512 + lane * 8);
        float4 e0 = er[0], e1 = er[1];
        float p = e0.x * hreg[0] + e0.y * hreg[1] + e0.z * hreg[2] + e0.w * hreg[3]
                + e1.x * hreg[4] + e1.y * hreg[5] + e1.z * hreg[6] + e1.w * hreg[7];
#pragma unroll
        for (int off = 32; off > 0; off >>= 1) p += __shfl_down(p, off);
        if (lane == 0) sc[s] = (P.x[b * NS + s] == 0) ? NEGV : p;
    }
    __syncthreads();
    red[t] = sc[t];
    __syncthreads();
    for (int sft = 128; sft > 0; sft >>= 1) { if (t < sft) red[t] = fmaxf(red[t], red[t + sft]); __syncthreads(); }
    float m = red[0];
    __syncthreads();
    float e = expf(sc[t] - m);
    red[t] = e;
    __syncthreads();
    for (int sft = 128; sft > 0; sft >>= 1) { if (t < sft) red[t] += red[t + sft]; __syncthreads(); }
    float inv = 1.f / red[0];
    float p_s = e * inv;
    sc[t] = p_s;
    P.attn8[(tstep * NR + jb) * NS + t] = p_s;
    __syncthreads();
    {
        float cp[8] = {0.f,0.f,0.f,0.f,0.f,0.f,0.f,0.f};
        const float* encw = encb + lane * 8;
        for (int s = wid * 64; s < wid * 64 + 64; s++) {
            float ps = sc[s];
            const float4* er = (const float4*)(encw + s * 512);
            float4 e0 = er[0], e1 = er[1];
            cp[0] += ps * e0.x; cp[1] += ps * e0.y; cp[2] += ps * e0.z; cp[3] += ps * e0.w;
            cp[4] += ps * e1.x; cp[5] += ps * e1.y; cp[6] += ps * e1.z; cp[7] += ps * e1.w;
        }
        float* cw = ctxp + wid * 512 + lane * 8;
#pragma unroll
        for (int i = 0; i < 8; i++) cw[i] = cp[i];
    }
    __syncthreads();
    int d0 = 2 * t, d1 = 2 * t + 1;
    float c0 = ctxp[d0] + ctxp[512 + d0] + ctxp[1024 + d0] + ctxp[1536 + d0];
    float c1 = ctxp[d1] + ctxp[512 + d1] + ctxp[1024 + d1] + ctxp[1536 + d1];
    if (tstep == 0) ((float2*)P.ctx0)[jb * 256 + t] = make_float2(c0, c1);
    float pg = P.wgenW[d0] * P.w_g[jb * 512 + d0] + P.wgenW[d1] * P.w_g[jb * 512 + d1]
             + P.wgenW[512 + d0] * h_lds[d0] + P.wgenW[512 + d1] * h_lds[d1]
             + P.wgenW[1024 + d0] * c0 + P.wgenW[1024 + d1] * c1;
    __syncthreads();
    red[t] = pg;
    __syncthreads();
    for (int sft = 128; sft > 0; sft >>= 1) { if (t < sft) red[t] += red[t + sft]; __syncthreads(); }
    if (t == 0) P.pgen8[tstep * NR + jb] = 1.f / (1.f + expf(-(red[0] + P.wgenb[0])));
}

// ---------------- phase: vocab GEMM + exp + rowsum + dense argmax; exp stays in LDS stash ----------------
#define VPAD 136
__device__ void phase_vgemm(int blk, const DecArgs& P, unsigned char* smem, int tstep) {
    unsigned short* A = (unsigned short*)smem;   // 160*136*2 = 43520 B: staging then exp stash
    int t = threadIdx.x;
    int wv = t >> 6, lane = t & 63, col15 = lane & 15, quad = lane >> 4;
    int v = blk * 128 + wv * 32 + col15;
    f32x4 acc[10][2];
#pragma unroll
    for (int m = 0; m < 10; m++) {
        acc[m][0] = (f32x4){0.f, 0.f, 0.f, 0.f};
        acc[m][1] = (f32x4){0.f, 0.f, 0.f, 0.f};
    }
    int v0c = min(v, V - 1);
    int v1c = min(v + 16, V - 1);
    for (int kc = 0; kc < 4; kc++) {
        __syncthreads();
        for (int i = t; i < 2560; i += 256) {
            int row = i >> 4, seg = i & 15;
            *(short8*)(A + row * VPAD + seg * 8) = *(const short8*)(P.h_hi + row * 512 + kc * 128 + seg * 8);
        }
        __syncthreads();
#pragma unroll
        for (int ks = 0; ks < 4; ks++) {
            int kl = ks * 32 + quad * 8;
            int kg = kc * 128 + kl;
            short8 b0 = *(const short8*)(P.emb_bf + (size_t)v0c * 512 + kg);
            short8 b1 = *(const short8*)(P.emb_bf + (size_t)v1c * 512 + kg);
#pragma unroll
            for (int m = 0; m < 10; m++) {
                short8 a = *(const short8*)(A + (m * 16 + col15) * VPAD + kl);
                acc[m][0] = __builtin_amdgcn_mfma_f32_16x16x32_bf16(a, b0, acc[m][0], 0, 0, 0);
                acc[m][1] = __builtin_amdgcn_mfma_f32_16x16x32_bf16(a, b1, acc[m][1], 0, 0, 0);
            }
        }
    }
    __syncthreads();
    // exp + transpose into LDS stash (bf16)
#pragma unroll
    for (int m = 0; m < 10; m++) {
#pragma unroll
        for (int tile = 0; tile < 2; tile++) {
            int vv = v + tile * 16;
            int cl = wv * 32 + tile * 16 + col15;
#pragma unroll
            for (int r = 0; r < 4; r++) {
                int row = m * 16 + quad * 4 + r;
                float ev = (vv < V) ? expf(acc[m][tile][r]) : 0.f;
                A[row * VPAD + cl] = f2bf(ev);
            }
        }
    }
    __syncthreads();
    if (t < NR) {
        float s = 0.f;
        unsigned long long key = 0ull;
#pragma unroll
        for (int seg = 0; seg < 16; seg++) {
            short8 ev = *(const short8*)(A + t * VPAD + seg * 8);
#pragma unroll
            for (int k = 0; k < 8; k++) {
                float f = bf2f((unsigned short)ev[k]);
                s += f;
                unsigned long long kk = packkey(f, blk * 128 + seg * 8 + k);
                key = (kk > key) ? kk : key;
            }
        }
        atomicAdd(P.rowsum8 + tstep * NR + t, s);
        atomicMax(P.argpk8 + tstep * NR + t, key);
    }
}

// ---------------- persistent decode kernel (plain launch, flag barriers) ----------------
__global__ __launch_bounds__(256, 2) void k_decode(DecArgs P) {
    __shared__ __align__(16) unsigned char smem[43520];
    __shared__ int            x_vvs[256];
    __shared__ float          x_as[256];
    __shared__ unsigned short x_hh[512];
    __shared__ float          x_scl[NR];
    __shared__ float          x_pg[NR];
    __shared__ float          x_bv[256];
    __shared__ int            x_bi[256];
    unsigned short* A = (unsigned short*)smem;
    int blk = blockIdx.x;
    int tid = threadIdx.x;
    for (int t = 0; t < NT; t++) {
        phase_gru(blk, P, smem);
        gbar(P.bars + t * 4 + 0);
        if (blk < NR) phase_attention(blk, P, smem, t);
        gbar(P.bars + t * 4 + 1);
        phase_vgemm(blk, P, smem, t);
        gbar(P.bars + t * 4 + 2);
        // scale table (all blocks need it for the out-write)
        if (tid < NR) {
            float rs = __hip_atomic_load(P.rowsum8 + t * NR + tid, __ATOMIC_RELAXED, __HIP_MEMORY_SCOPE_AGENT);
            float pg = __hip_atomic_load(P.pgen8 + t * NR + tid, __ATOMIC_RELAXED, __HIP_MEMORY_SCOPE_AGENT);
            x_scl[tid] = pg * (1.f / rs);
            x_pg[tid]  = pg;
        }
        __syncthreads();
        // ---- w_next: scatter candidates (recomputed logits) + dense argmax -> w(t+1) ----
        if (blk < NR) {
            int jb = blk, b = jb & 15;
            ((unsigned int*)x_hh)[tid] = ((const unsigned int*)(P.h_hi + jb * 512))[tid];
            int vv = P.x[b * NS + tid];
            float a = (1.f - x_pg[jb]) * P.attn8[(t * NR + jb) * NS + tid];
            x_vvs[tid] = vv; x_as[tid] = a;
            __syncthreads();
            float sum = 0.f;
            for (int s2 = 0; s2 < 256; s2++)
                if (x_vvs[s2] == vv) sum += x_as[s2];
            float lg = 0.f;
            const unsigned short* er = P.emb_bf + (size_t)vv * 512;
            for (int k = 0; k < 512; k += 8) {
                short8 e = *(const short8*)(er + k);
                short8 h8 = *(const short8*)(x_hh + k);
#pragma unroll
                for (int i = 0; i < 8; i++) lg += bf2f((unsigned short)e[i]) * bf2f((unsigned short)h8[i]);
            }
            float scale = x_scl[jb];
            float cand = scale * bf2f(f2bf(expf(lg))) + sum;   // mirror R4: dense part bf16-rounded
            x_bv[tid] = cand; x_bi[tid] = vv;
            __syncthreads();
            for (int sft = 128; sft > 0; sft >>= 1) {
                if (tid < sft) {
                    if (x_bv[tid + sft] > x_bv[tid] || (x_bv[tid + sft] == x_bv[tid] && x_bi[tid + sft] < x_bi[tid])) {
                        x_bv[tid] = x_bv[tid + sft]; x_bi[tid] = x_bi[tid + sft];
                    }
                }
                __syncthreads();
            }
            unsigned long long key = __hip_atomic_load(P.argpk8 + t * NR + jb, __ATOMIC_RELAXED, __HIP_MEMORY_SCOPE_AGENT);
            union { unsigned int u; float f; } c; c.u = (unsigned int)(key >> 32);
            float db = c.f * scale;
            int di = 0x7FFFFFFF - (int)(key & 0xFFFFFFFFu);
            float sb = x_bv[0]; int si = x_bi[0];
            int widx = (sb > db || (sb == db && si < di)) ? si : di;
            for (int d = tid; d < 512; d += 256) {
                float val = P.embW[(size_t)widx * 512 + d];
                P.w_g[jb * 512 + d] = val;
                unsigned short hi = f2bf(val);
                P.w_hi[jb * 512 + d] = hi;
                P.w_lo[jb * 512 + d] = f2bf(val - bf2f(hi));
            }
        }
        gbar(P.bars + t * 4 + 3);   // w(t+1) ready; out-writes below overlap next step
        // ---- dense out write (scaled, from LDS stash), off the critical path ----
        int c0 = blk * 128;
        if (c0 < V) {
            int colpair = (tid & 63) * 2;
            int rbase = tid >> 6;
            bool valid = (c0 + colpair) < V;
            for (int it = 0; it < 40; it++) {
                int row = rbase + it * 4;
                float sc = x_scl[row];
                unsigned int u = *(const unsigned int*)(A + row * VPAD + colpair);
                if (valid) {
                    int j = row >> 4, b = row & 15;
                    float* op = P.out + 640 + ((size_t)((b * NJ + j) * NT + t)) * V;
                    float2 pv = make_float2(bf2f((unsigned short)(u & 0xffff)) * sc,
                                            bf2f((unsigned short)(u >> 16)) * sc);
                    *(float2*)(op + c0 + colpair) = pv;
                }
            }
        }
        __syncthreads();   // drain dense stores before scatter atomics to same lines
        // ---- pointer scatter: owner-block adds for its column range ----
        for (int i = tid; i < NB * NS; i += 256) {
            int vv = P.x[i];
            if ((vv >> 7) == blk) {
                int b = i >> 8, s = i & 255;
#pragma unroll
                for (int j = 0; j < NJ; j++) {
                    int row = j * 16 + b;
                    float a = (1.f - x_pg[row]) * P.attn8[(t * NR + row) * NS + s];
                    atomicAdd(P.out + 640 + ((size_t)((b * NJ + j) * NT + t)) * V + vv, a);
                }
            }
        }
        // ---- gate head (step-0 context) ----
        if (t == 0 && blk < NR) {
            int jb = blk, j = jb >> 4, b = jb & 15;
            float part[4] = {0.f, 0.f, 0.f, 0.f};
            for (int d = tid; d < 512; d += 256) {
                float cc = P.ctx0[jb * 512 + d];
#pragma unroll
                for (int o = 0; o < 4; o++) part[o] += cc * P.aW[o * 512 + d];
            }
            for (int o = 0; o < 4; o++) {
                __syncthreads();
                x_bv[tid] = part[o];
                __syncthreads();
                for (int sft = 128; sft > 0; sft >>= 1) { if (tid < sft) x_bv[tid] += x_bv[tid + sft]; __syncthreads(); }
                if (tid == 0) P.out[(b * NJ + j) * NOPS + o] = x_bv[0] + P.ab[o];
            }
        }
        __syncthreads();   // protect LDS stash until all waves done before next gru staging
    }
}

extern "C" void kernel_launch(void* const* d_in, const int* in_sizes, int n_in,
                              void* d_out, int out_size, void* d_ws, size_t ws_size,
                              hipStream_t stream) {
    const int*   x     = (const int*)d_in[0];
    const float* enc   = (const float*)d_in[1];
    const float* ench  = (const float*)d_in[2];
    const float* embW  = (const float*)d_in[4];
    const float* slot  = (const float*)d_in[5];
    const float* Wih   = (const float*)d_in[6];
    const float* Whh   = (const float*)d_in[7];
    const float* bih   = (const float*)d_in[8];
    const float* bhh   = (const float*)d_in[9];
    const float* wgenW = (const float*)d_in[10];
    const float* wgenb = (const float*)d_in[11];
    const float* aW    = (const float*)d_in[12];
    const float* ab    = (const float*)d_in[13];
    float* out = (float*)d_out;

    char* ws = (char*)d_ws;
    size_t off = 0;
    auto carve = [&](size_t bytes) { char* p = ws + off; off += (bytes + 255) & ~(size_t)255; return p; };
    unsigned short* emb_bf = (unsigned short*)carve((size_t)V * H * 2);
    unsigned short* wih_hi = (unsigned short*)carve(786432 * 2);
    unsigned short* wih_lo = (unsigned short*)carve(786432 * 2);
    unsigned short* whh_hi = (unsigned short*)carve(786432 * 2);
    unsigned short* whh_lo = (unsigned short*)carve(786432 * 2);
    float* w_f32 = (float*)carve(NR * H * 4);
    float* h_f32 = (float*)carve(NR * H * 4);
    float* ctx0  = (float*)carve(NR * H * 4);
    unsigned short* w_hi = (unsigned short*)carve(NR * H * 2);
    unsigned short* w_lo = (unsigned short*)carve(NR * H * 2);
    unsigned short* h_hi = (unsigned short*)carve(NR * H * 2);
    unsigned short* h_lo = (unsigned short*)carve(NR * H * 2);
    float* gi   = (float*)carve(NR * 1536 * 4);
    float* gh   = (float*)carve(NR * 1536 * 4);
    float* attn8 = (float*)carve((size_t)NT * NR * NS * 4);
    float* pgen8 = (float*)carve(NT * NR * 4);
    float* rowsum8 = (float*)carve(NT * NR * 4);
    unsigned long long* argpk8 = (unsigned long long*)carve(NT * NR * 8);
    unsigned int* bars = (unsigned int*)carve(64 * 4);

    k_setup_emb<<<7500, 256, 0, stream>>>(embW, emb_bf, (V * H) / 8);
    int setup_threads = 786432 + NR * H + 64 + 2 * NT * NR;
    k_setup_small<<<(setup_threads + 255) / 256, 256, 0, stream>>>(
        Wih, Whh, wih_hi, wih_lo, whh_hi, whh_lo, slot, ench,
        w_f32, w_hi, w_lo, h_f32, h_hi, h_lo, bars, rowsum8, argpk8);

    DecArgs P;
    P.x = x; P.enc = enc; P.embW = embW;
    P.bih = bih; P.bhh = bhh; P.wgenW = wgenW; P.wgenb = wgenb;
    P.aW = aW; P.ab = ab;
    P.emb_bf = emb_bf;
    P.wih_hi = wih_hi; P.wih_lo = wih_lo; P.whh_hi = whh_hi; P.whh_lo = whh_lo;
    P.w_g = w_f32; P.h_g = h_f32; P.ctx0 = ctx0;
    P.w_hi = w_hi; P.w_lo = w_lo; P.h_hi = h_hi; P.h_lo = h_lo;
    P.gi = gi; P.gh = gh;
    P.attn8 = attn8; P.pgen8 = pgen8;
    P.rowsum8 = rowsum8; P.argpk8 = argpk8;
    P.bars = bars; P.out = out;

    k_decode<<<NBLK, 256, 0, stream>>>(P);
}